// Round 7
// baseline (301.158 us; speedup 1.0000x reference)
//
#include <hip/hip_runtime.h>
#include <math.h>

// RecurNN: B=256, L=256, E=100, T=255.
// x_t = W1L*left_t + W1R*right_t + b1; h_t = tanh(x_t); out = sigmoid(W2 h_254 + b2).
// For these inputs: right_t always a leaf; left_t = node t-1 (leaf only at t=0).
//
// Register-residency law (R1/R4/R5/R6): <=100 NAMED SCALAR floats promote to
// VGPRs (R6: VGPR_Count=132, resident). Arrays / float2 / asm-pairs spill.
//
// phaseA (parallel): c[task][e] = b1[e] + W1R[e]*emb[right] (+W1L*emb[left] leaf).
//   1020 blocks x 128 thr, 3 waves/SIMD min occupancy for latency hiding.
// phaseB (sequential): 256 blocks x 128 thr (2 waves); thread e owns W1L row
//   (100 named scalars); h history in LDS (wave-uniform b128 broadcasts);
//   c prefetched 8 STEPS AHEAD into named registers (statically unrolled) so
//   the global load latency (the R6 killer) amortizes to ~60 cyc/step.

#define Bc 256
#define Lc 256
#define Ec 100
#define Tc 255
#define W1cols 200

#define REP25(X) X(0) X(1) X(2) X(3) X(4) X(5) X(6) X(7) X(8) X(9) X(10) X(11) X(12) \
                 X(13) X(14) X(15) X(16) X(17) X(18) X(19) X(20) X(21) X(22) X(23) X(24)

#define DECLW(q) float wx##q, wy##q, wz##q, ww##q;
#define LOADW(q) { float4 t4 = *(const float4*)(wrow + 4*(q)); \
                   wx##q = t4.x; wy##q = t4.y; wz##q = t4.z; ww##q = t4.w; }
#define MV(q)    { float4 h4 = *(const float4*)(rp + 4*(q)); \
                   a0 = fmaf(wx##q, h4.x, a0); a1 = fmaf(wy##q, h4.y, a1); \
                   a2 = fmaf(wz##q, h4.z, a2); a3 = fmaf(ww##q, h4.w, a3); }

// generic fallback matvec (weights from global; never hit by these inputs)
__device__ __forceinline__ void slowAccum(const float* rp, const float* wr,
                                          float& a0, float& a1, float& a2, float& a3) {
    for (int qq = 0; qq < 25; ++qq) {
        float4 h4 = *(const float4*)(rp + 4 * qq);
        float4 w4 = *(const float4*)(wr + 4 * qq);
        a0 = fmaf(w4.x, h4.x, a0); a1 = fmaf(w4.y, h4.y, a1);
        a2 = fmaf(w4.z, h4.z, a2); a3 = fmaf(w4.w, h4.w, a3);
    }
}

// ======================= phaseA =======================
__global__ __launch_bounds__(128, 3)
void phaseA(const int* __restrict__ token_ids,
            const int* __restrict__ comp_left,
            const int* __restrict__ comp_right,
            const float* __restrict__ emb,
            const float* __restrict__ W1,
            const float* __restrict__ b1,
            float* __restrict__ c_ws)
{
    const int tid = threadIdx.x;
    const int e   = tid;                 // output row; active < 100
    const bool act = (e < Ec);
    const int ee  = act ? e : 0;
    const int base = blockIdx.x * 64;

    __shared__ int tokR[64], tokL[64], criS[64], cliS[64];

    if (tid < 64) {
        const int task = base + tid;
        const int bq = task / Tc;
        const int cr = comp_right[task];
        const int cl = comp_left[task];
        criS[tid] = cr;  cliS[tid] = cl;
        tokR[tid] = token_ids[bq * Lc + min(cr, Lc - 1)];
        tokL[tid] = token_ids[bq * Lc + min(cl, Lc - 1)];
    }
    __syncthreads();

    const float* wrow = W1 + (size_t)ee * W1cols + Ec;   // W1R row e
    REP25(DECLW)
    REP25(LOADW)
    const float b1e = act ? b1[e] : 0.f;

    #pragma unroll 2
    for (int q = 0; q < 64; ++q) {
        float a0 = b1e, a1 = 0.f, a2 = 0.f, a3 = 0.f;
        if (criS[q] < Lc) {              // right leaf (always, these inputs)
            const float* rp = emb + (size_t)tokR[q] * Ec;
            REP25(MV)
        }
        if (cliS[q] < Lc)                // left leaf (t==0 only) — generic
            slowAccum(emb + (size_t)tokL[q] * Ec, W1 + (size_t)ee * W1cols, a0, a1, a2, a3);
        if (act)
            c_ws[(size_t)(base + q) * Ec + e] = (a0 + a1) + (a2 + a3);
    }
}

// ======================= phaseB =======================
__global__ __launch_bounds__(128, 1)
void phaseB(const int* __restrict__ comp_left,
            const int* __restrict__ comp_right,
            const float* __restrict__ W1,
            const float* __restrict__ W2,
            const float* __restrict__ b2,
            const float* __restrict__ c_ws,
            float* __restrict__ out)
{
    const int b   = blockIdx.x;
    const int tid = threadIdx.x;         // 0..127, 2 waves
    const int e   = tid;
    const bool act = (e < Ec);
    const int ee  = act ? e : 0;         // OOB-safe column for c_ws reads

    __shared__ __align__(16) float hist[Tc * Ec];   // 102000 B node history
    __shared__ int2  ccS[Tc];
    __shared__ float red[2];

    for (int i = tid; i < Tc; i += 128)
        ccS[i] = make_int2(comp_left[b * Tc + i], comp_right[b * Tc + i]);
    {   // zero-init: unwritten nodes must read as 0 (reference zero-pads buf)
        const float4 z4 = make_float4(0.f, 0.f, 0.f, 0.f);
        for (int i = tid; i < (Tc * Ec) / 4; i += 128) ((float4*)hist)[i] = z4;
    }

    const float* wrow = W1 + (size_t)ee * W1cols;   // W1L row e
    REP25(DECLW)
    REP25(LOADW)
    const float w2e = act ? W2[e] : 0.f;

    const float* cb = c_ws + (size_t)b * Tc * Ec;
    // c register pipeline: 8 named scalars current group + 8 next (static idx)
    float cc0 = cb[0*Ec+ee], cc1 = cb[1*Ec+ee], cc2 = cb[2*Ec+ee], cc3 = cb[3*Ec+ee];
    float cc4 = cb[4*Ec+ee], cc5 = cb[5*Ec+ee], cc6 = cb[6*Ec+ee], cc7 = cb[7*Ec+ee];
    __syncthreads();                     // hist/ccS ready

    float h = 0.f;

#define STEP(j, cj)                                                          \
    if (t0 + (j) < Tc) {                                                     \
        const int   t  = t0 + (j);                                           \
        const int2  cc = ccS[t];                                             \
        const int   li = __builtin_amdgcn_readfirstlane(cc.x);               \
        const int   ri = __builtin_amdgcn_readfirstlane(cc.y);               \
        float a0 = (cj), a1 = 0.f, a2 = 0.f, a3 = 0.f;                       \
        if (li >= Lc) { const float* rp = &hist[(li - Lc) * Ec]; REP25(MV) } \
        if (ri >= Lc)                                                        \
            slowAccum(&hist[(ri - Lc) * Ec],                                 \
                      W1 + (size_t)ee * W1cols + Ec, a0, a1, a2, a3);        \
        const float x = (a0 + a1) + (a2 + a3);                               \
        const float u = __expf(2.f * x);                                     \
        h = 1.f - 2.f / (u + 1.f);                                           \
        if (act) hist[t * Ec + e] = h;                                       \
        __syncthreads();                                                     \
    }

    #pragma unroll 1
    for (int t0 = 0; t0 < Tc; t0 += 8) {
        // prefetch next group's c (8 independent loads, ~8 steps to land)
        const float nn0 = cb[(size_t)min(t0 +  8, Tc - 1) * Ec + ee];
        const float nn1 = cb[(size_t)min(t0 +  9, Tc - 1) * Ec + ee];
        const float nn2 = cb[(size_t)min(t0 + 10, Tc - 1) * Ec + ee];
        const float nn3 = cb[(size_t)min(t0 + 11, Tc - 1) * Ec + ee];
        const float nn4 = cb[(size_t)min(t0 + 12, Tc - 1) * Ec + ee];
        const float nn5 = cb[(size_t)min(t0 + 13, Tc - 1) * Ec + ee];
        const float nn6 = cb[(size_t)min(t0 + 14, Tc - 1) * Ec + ee];
        const float nn7 = cb[(size_t)min(t0 + 15, Tc - 1) * Ec + ee];

        STEP(0, cc0) STEP(1, cc1) STEP(2, cc2) STEP(3, cc3)
        STEP(4, cc4) STEP(5, cc5) STEP(6, cc6) STEP(7, cc7)

        cc0 = nn0; cc1 = nn1; cc2 = nn2; cc3 = nn3;
        cc4 = nn4; cc5 = nn5; cc6 = nn6; cc7 = nn7;
    }
#undef STEP

    // out[b] = sigmoid(W2 . h_254 + b2): 2-wave reduction
    float p = act ? w2e * h : 0.f;
    #pragma unroll
    for (int off = 32; off > 0; off >>= 1) p += __shfl_down(p, off, 64);
    if ((tid & 63) == 0) red[tid >> 6] = p;
    __syncthreads();
    if (tid == 0) out[b] = 1.f / (1.f + __expf(-(red[0] + red[1] + b2[0])));
}

extern "C" void kernel_launch(void* const* d_in, const int* in_sizes, int n_in,
                              void* d_out, int out_size, void* d_ws, size_t ws_size,
                              hipStream_t stream) {
    const int*   token_ids  = (const int*)  d_in[0];
    const int*   comp_left  = (const int*)  d_in[1];
    const int*   comp_right = (const int*)  d_in[2];
    const float* emb        = (const float*)d_in[3];
    const float* W1         = (const float*)d_in[4];
    const float* b1         = (const float*)d_in[5];
    const float* W2         = (const float*)d_in[6];
    const float* b2         = (const float*)d_in[7];
    float*       out        = (float*)d_out;
    float*       c_ws       = (float*)d_ws;   // B*T*E*4 = 26,112,000 B <= ws_size

    phaseA<<<(Bc * Tc) / 64, 128, 0, stream>>>(token_ids, comp_left, comp_right,
                                               emb, W1, b1, c_ws);
    phaseB<<<Bc, 128, 0, stream>>>(comp_left, comp_right, W1, W2, b2, c_ws, out);
}

// Round 8
// 289.724 us; speedup vs baseline: 1.0395x; 1.0395x over previous
//
#include <hip/hip_runtime.h>
#include <math.h>

// RecurNN: B=256, L=256, E=100, T=255.
// x_t = W1L*left_t + W1R*right_t + b1; h_t = tanh(x_t); out = sigmoid(W2 h_254 + b2).
// For these inputs: right_t always a leaf; left_t = node t-1 (leaf only at t=0).
//
// FUSED producer/consumer, ONE kernel, one block per batch row, 192 threads:
//  wave 0  (consumer): the sequential recurrence. Lane l owns rows 2l,2l+1 with
//    BOTH W1L rows in 200 named scalar VGPRs (m08: no spill through 450 regs).
//    Per step: 25 wave-uniform ds_read_b128 of h(t-1) from LDS hist, 200 fma,
//    tanh, ds_write h. No barriers, no shuffles, single wave.
//  waves 1,2 (producers): c_t = b1 + [leaf] W1R*emb (+W1L*emb at t=0) into a
//    64-deep LDS ring, running ahead; wave1 rows 0-63, wave2 rows 64-99.
//  Sync: monotonic LDS flags (vf[0],vf[1] = producer progress, vf[2] = consumer
//    progress). DS pipe is in-order per wave => flag-after-data publishes safely.

#define Bc 256
#define Lc 256
#define Ec 100
#define Tc 255
#define W1cols 200
#define RC 64            // c-ring depth (slots)

#define REP25(X) X(0) X(1) X(2) X(3) X(4) X(5) X(6) X(7) X(8) X(9) X(10) X(11) X(12) \
                 X(13) X(14) X(15) X(16) X(17) X(18) X(19) X(20) X(21) X(22) X(23) X(24)

// ---- producer weights: one row (100 named scalars) ----
#define DECLW(q) float wx##q, wy##q, wz##q, ww##q;
#define LOADW(q) { float4 t4 = *(const float4*)(wrow + 4*(q)); \
                   wx##q = t4.x; wy##q = t4.y; wz##q = t4.z; ww##q = t4.w; }
#define MV(q)    { float4 h4 = *(const float4*)(rp + 4*(q)); \
                   a0 = fmaf(wx##q, h4.x, a0); a1 = fmaf(wy##q, h4.y, a1); \
                   a2 = fmaf(wz##q, h4.z, a2); a3 = fmaf(ww##q, h4.w, a3); }

// ---- consumer weights: two rows (200 named scalars) ----
#define DECLA(q) float Ax##q, Ay##q, Az##q, Aw##q, Bx##q, By##q, Bz##q, Bw##q;
#define LOADA(q) { float4 u4 = *(const float4*)(rA + 4*(q)); \
                   Ax##q = u4.x; Ay##q = u4.y; Az##q = u4.z; Aw##q = u4.w; \
                   float4 v4 = *(const float4*)(rB + 4*(q)); \
                   Bx##q = v4.x; By##q = v4.y; Bz##q = v4.z; Bw##q = v4.w; }
#define MV2(q)   { float4 h4 = *(const float4*)(rp + 4*(q)); \
                   a0 = fmaf(Ax##q, h4.x, a0); a1 = fmaf(Ay##q, h4.y, a1); \
                   a2 = fmaf(Az##q, h4.z, a2); a3 = fmaf(Aw##q, h4.w, a3); \
                   b0 = fmaf(Bx##q, h4.x, b0); b1a = fmaf(By##q, h4.y, b1a); \
                   b2a = fmaf(Bz##q, h4.z, b2a); b3 = fmaf(Bw##q, h4.w, b3); }

__global__ __launch_bounds__(192, 1)
void fused(const int* __restrict__ token_ids,
           const int* __restrict__ comp_left,
           const int* __restrict__ comp_right,
           const float* __restrict__ emb,
           const float* __restrict__ W1,
           const float* __restrict__ b1,
           const float* __restrict__ W2,
           const float* __restrict__ b2,
           float* __restrict__ out)
{
    const int b   = blockIdx.x;
    const int tid = threadIdx.x;         // 0..191 (3 waves)

    __shared__ __align__(16) float hist[Tc * Ec];     // 102000 B full history
    __shared__ __align__(16) float cring[RC][Ec];     // 25600 B c ring
    __shared__ int2 ccS[Tc];                          // comp indices
    __shared__ int  tokRt[Tc], tokLt[Tc];             // token of leaf refs (-1 = internal)
    __shared__ int  flags[4];                         // [0]=prodW1 [1]=prodW2 [2]=cons

    // ---- init (all 3 waves) ----
    for (int i = tid; i < Tc; i += 192) {
        const int cl = comp_left [b * Tc + i];
        const int cr = comp_right[b * Tc + i];
        ccS[i] = make_int2(cl, cr);
        tokRt[i] = (cr < Lc) ? token_ids[b * Lc + cr] : -1;
        tokLt[i] = (cl < Lc) ? token_ids[b * Lc + cl] : -1;
    }
    {
        const float4 z4 = make_float4(0.f, 0.f, 0.f, 0.f);
        for (int i = tid; i < (Tc * Ec) / 4; i += 192) ((float4*)hist)[i] = z4;
    }
    if (tid < 4) flags[tid] = 0;
    volatile int* vf = flags;
    __syncthreads();     // the ONLY barrier in the kernel

    if (tid < 64) {
        // ================= CONSUMER (wave 0) =================
        const int l   = tid;
        const bool act = (l < 50);
        const int rowA = act ? 2 * l : Ec - 2;
        const float* rA = W1 + (size_t)rowA * W1cols;        // W1L row 2l
        const float* rB = W1 + (size_t)(rowA + 1) * W1cols;  // W1L row 2l+1
        REP25(DECLA)
        REP25(LOADA)
        const float w2a = act ? W2[rowA]     : 0.f;
        const float w2b = act ? W2[rowA + 1] : 0.f;
        const float b2v = b2[0];

        // wait for c_0, then grab it
        while (vf[0] < 1 || vf[1] < 1) {}
        asm volatile("" ::: "memory");
        float2 cp = *(const float2*)&cring[0][act ? 2 * l : 0];
        if (l == 0) vf[2] = 1;

        int2 cc = ccS[0];
        float ha = 0.f, hb = 0.f;

        #pragma unroll 1
        for (int t = 0; t < Tc; ++t) {
            const int li = __builtin_amdgcn_readfirstlane(cc.x);
            const int ri = __builtin_amdgcn_readfirstlane(cc.y);
            float a0 = 0.f, a1 = 0.f, a2 = 0.f, a3 = 0.f;
            float b0 = 0.f, b1a = 0.f, b2a = 0.f, b3 = 0.f;

            if (li >= Lc) {                   // left internal: fast path (W1L regs)
                const float* rp = &hist[(size_t)min(li - Lc, Tc - 1) * Ec];
                REP25(MV2)
            }
            if (ri >= Lc) {                   // right internal: generic slow path
                const float* rp = &hist[(size_t)min(ri - Lc, Tc - 1) * Ec];
                const float* wa = W1 + (size_t)rowA * W1cols + Ec;
                const float* wb = W1 + (size_t)(rowA + 1) * W1cols + Ec;
                for (int qq = 0; qq < 25; ++qq) {
                    float4 h4 = *(const float4*)(rp + 4 * qq);
                    float4 w4 = *(const float4*)(wa + 4 * qq);
                    float4 v4 = *(const float4*)(wb + 4 * qq);
                    a0 = fmaf(w4.x, h4.x, a0); a1 = fmaf(w4.y, h4.y, a1);
                    a2 = fmaf(w4.z, h4.z, a2); a3 = fmaf(w4.w, h4.w, a3);
                    b0 = fmaf(v4.x, h4.x, b0); b1a = fmaf(v4.y, h4.y, b1a);
                    b2a = fmaf(v4.z, h4.z, b2a); b3 = fmaf(v4.w, h4.w, b3);
                }
            }

            const float xa = ((a0 + a1) + (a2 + a3)) + cp.x;
            const float xb = ((b0 + b1a) + (b2a + b3)) + cp.y;
            const float ua = __expf(2.f * xa);
            const float ub = __expf(2.f * xb);
            ha = 1.f - 2.f / (ua + 1.f);      // tanh, exact identity
            hb = 1.f - 2.f / (ub + 1.f);
            if (act) *(float2*)&hist[(size_t)t * Ec + 2 * l] = make_float2(ha, hb);

            if (t + 1 < Tc) {
                cc = ccS[t + 1];
                while (vf[0] < t + 2 || vf[1] < t + 2) {}      // usually immediate
                asm volatile("" ::: "memory");
                cp = *(const float2*)&cring[(t + 1) & (RC - 1)][act ? 2 * l : 0];
                if (l == 0) vf[2] = t + 2;
            }
        }

        // out[b] = sigmoid(W2 . h_254 + b2)
        float p = act ? (w2a * ha + w2b * hb) : 0.f;
        #pragma unroll
        for (int off = 1; off < 64; off <<= 1) p += __shfl_xor(p, off, 64);
        if (l == 0) out[b] = 1.f / (1.f + __expf(-(p + b2v)));

    } else {
        // ================= PRODUCERS (waves 1,2) =================
        const int e   = tid - 64;            // wave1: 0..63, wave2: 64..127
        const bool pact = (e < Ec);
        const int ep  = pact ? e : 0;
        const float* wrow = W1 + (size_t)ep * W1cols + Ec;    // W1R row e
        REP25(DECLW)
        REP25(LOADW)
        const float b1e = pact ? b1[e] : 0.f;

        #pragma unroll 2
        for (int t = 0; t < Tc; ++t) {
            const int s = t & (RC - 1);
            if (t >= RC) { while (vf[2] < t - (RC - 1)) {} }   // ring-slot free?
            const int rt = __builtin_amdgcn_readfirstlane(tokRt[t]);
            const int lt = __builtin_amdgcn_readfirstlane(tokLt[t]);

            float a0 = b1e, a1 = 0.f, a2 = 0.f, a3 = 0.f;
            if (rt >= 0) {                    // right leaf (always, these inputs)
                const float* rp = emb + (size_t)rt * Ec;
                REP25(MV)
            }
            if (lt >= 0) {                    // left leaf (t==0 only): W1L from global
                const float* rp2 = emb + (size_t)lt * Ec;
                const float* wl  = W1 + (size_t)ep * W1cols;
                for (int qq = 0; qq < 25; ++qq) {
                    float4 h4 = *(const float4*)(rp2 + 4 * qq);
                    float4 w4 = *(const float4*)(wl + 4 * qq);
                    a0 = fmaf(w4.x, h4.x, a0); a1 = fmaf(w4.y, h4.y, a1);
                    a2 = fmaf(w4.z, h4.z, a2); a3 = fmaf(w4.w, h4.w, a3);
                }
            }
            if (pact) cring[s][e] = (a0 + a1) + (a2 + a3);
            asm volatile("" ::: "memory");    // keep flag write after data write
            if (tid == 64)  vf[0] = t + 1;    // wave1 done (rows 0-63)
            if (tid == 128) vf[1] = t + 1;    // wave2 done (rows 64-99)
        }
    }
}

extern "C" void kernel_launch(void* const* d_in, const int* in_sizes, int n_in,
                              void* d_out, int out_size, void* d_ws, size_t ws_size,
                              hipStream_t stream) {
    const int*   token_ids  = (const int*)  d_in[0];
    const int*   comp_left  = (const int*)  d_in[1];
    const int*   comp_right = (const int*)  d_in[2];
    const float* emb        = (const float*)d_in[3];
    const float* W1         = (const float*)d_in[4];
    const float* b1         = (const float*)d_in[5];
    const float* W2         = (const float*)d_in[6];
    const float* b2         = (const float*)d_in[7];
    float*       out        = (float*)d_out;

    fused<<<Bc, 192, 0, stream>>>(token_ids, comp_left, comp_right,
                                  emb, W1, b1, W2, b2, out);
}

// Round 9
// 183.293 us; speedup vs baseline: 1.6430x; 1.5807x over previous
//
#include <hip/hip_runtime.h>
#include <math.h>

// RecurNN: B=256, L=256, E=100, T=255.
// x_t = W1L*left_t + W1R*right_t + b1; h_t = tanh(x_t); out = sigmoid(W2 h_254 + b2).
// These inputs: right_t always a leaf; left_t = node t-1 (leaf only at t=0).
//
// ONE fused kernel, one block per batch row, 256 thr = 4 waves (1/SIMD):
//   waves 0,1 (consumers): recurrence. Lane l of wave w owns row e=50w+l with
//     W1L[e][:] in 100 named scalar VGPRs. h broadcast via v_readlane (VALU),
//     NOT LDS quads: lane k holds h[k] -> readlane(vh/vo, k) gives SGPR operand
//     for v_fmac. One ds_read_b32 + one ds_write_b32 per step. No LDS streams.
//   waves 2,3 (producers): c[t] = b1 + W1R*emb[right leaf]. emb row fetched as
//     per-lane COALESCED global b32 (lane k <- emb[tok][k]), double-buffered one
//     step ahead, then same readlane+fmac pattern. Writes 4-slot LDS c-ring.
//   Sync: one "s_waitcnt lgkmcnt(0); s_barrier" per step (NO vmcnt drain ->
//     producer prefetch survives the barrier). No spin-wait flags.

#define Bc 256
#define Lc 256
#define Ec 100
#define Tc 255
#define W1cols 200
#define LEAD 2

#define RL(v, k) __int_as_float(__builtin_amdgcn_readlane(__float_as_int(v), (k)))

#define REP100(X) \
 X(0,0) X(1,1) X(2,2) X(3,3) X(4,0) X(5,1) X(6,2) X(7,3) \
 X(8,0) X(9,1) X(10,2) X(11,3) X(12,0) X(13,1) X(14,2) X(15,3) \
 X(16,0) X(17,1) X(18,2) X(19,3) X(20,0) X(21,1) X(22,2) X(23,3) \
 X(24,0) X(25,1) X(26,2) X(27,3) X(28,0) X(29,1) X(30,2) X(31,3) \
 X(32,0) X(33,1) X(34,2) X(35,3) X(36,0) X(37,1) X(38,2) X(39,3) \
 X(40,0) X(41,1) X(42,2) X(43,3) X(44,0) X(45,1) X(46,2) X(47,3) \
 X(48,0) X(49,1) X(50,2) X(51,3) X(52,0) X(53,1) X(54,2) X(55,3) \
 X(56,0) X(57,1) X(58,2) X(59,3) X(60,0) X(61,1) X(62,2) X(63,3) \
 X(64,0) X(65,1) X(66,2) X(67,3) X(68,0) X(69,1) X(70,2) X(71,3) \
 X(72,0) X(73,1) X(74,2) X(75,3) X(76,0) X(77,1) X(78,2) X(79,3) \
 X(80,0) X(81,1) X(82,2) X(83,3) X(84,0) X(85,1) X(86,2) X(87,3) \
 X(88,0) X(89,1) X(90,2) X(91,3) X(92,0) X(93,1) X(94,2) X(95,3) \
 X(96,0) X(97,1) X(98,2) X(99,3)

#define DECLW(k, c) float w##k;
// generic / producer: 100-vector in vA (lanes 0-63 = k 0-63) + vB (lanes 0-35 = k 64-99)
#define MACCP(k, c) acc##c = fmaf(RL((k) < 64 ? vA : vB, (k) < 64 ? (k) : (k) - 64), w##k, acc##c);
// consumer fast path, wave 0: own half k<50 in vh (lane k), other half in vo (lane k-50)
#define MACC0(k, c) acc##c = fmaf(RL((k) < 50 ? vh : vo, (k) < 50 ? (k) : (k) - 50), w##k, acc##c);
// consumer fast path, wave 1: k<50 in vo (lane k), own half k>=50 in vh (lane k-50)
#define MACC1(k, c) acc##c = fmaf(RL((k) < 50 ? vo : vh, (k) < 50 ? (k) : (k) - 50), w##k, acc##c);

__global__ __launch_bounds__(256, 1)
void fused(const int* __restrict__ token_ids,
           const int* __restrict__ comp_left,
           const int* __restrict__ comp_right,
           const float* __restrict__ emb,
           const float* __restrict__ W1,
           const float* __restrict__ b1,
           const float* __restrict__ W2,
           const float* __restrict__ b2,
           float* __restrict__ out)
{
    const int b    = blockIdx.x;
    const int tid  = threadIdx.x;
    const int wv   = tid >> 6;            // 0,1 consumers; 2,3 producers
    const int l    = tid & 63;
    const bool cons = (wv < 2);
    const int lc   = (l < 50) ? l : 49;   // clamped row-lane

    __shared__ __align__(16) float hist[Tc * Ec];   // 102000 B (zero = unwritten)
    __shared__ float cring[4][Ec];                  // 1600 B c ring (4 slots)
    __shared__ int2  ccS[Tc];                       // comp indices
    __shared__ int   tokRS[Tc], tokLS[Tc];          // leaf tokens (-1 = internal)
    __shared__ float red[2];

    // ---- prologue staging (all waves) ----
    for (int i = tid; i < Tc; i += 256) {
        const int cl = comp_left [b * Tc + i];
        const int cr = comp_right[b * Tc + i];
        ccS[i]   = make_int2(cl, cr);
        tokRS[i] = (cr < Lc) ? token_ids[b * Lc + cr] : -1;
        tokLS[i] = (cl < Lc) ? token_ids[b * Lc + cl] : -1;
    }
    {   const float4 z4 = make_float4(0.f, 0.f, 0.f, 0.f);
        for (int i = tid; i < (Tc * Ec) / 4; i += 256) ((float4*)hist)[i] = z4;
    }

    // ---- role weights: consumer = W1L row, producer = W1R row (100 named scalars) ----
    const int erow = cons ? (50 * wv + lc) : (50 * (wv - 2) + lc);
    const float* wrow = W1 + (size_t)erow * W1cols + (cons ? 0 : Ec);
    REP100(DECLW)
#define LOADW(k, c) w##k = wrow[k];
    REP100(LOADW)
#undef LOADW
    const float b1e = b1[erow];
    const float w2e = W2[erow];

    __syncthreads();    // staging + weights visible

    // producer prefetch state (emb row k-distributed across lanes)
    float vA = 0.f, vB = 0.f;
    if (!cons) {
        const int t0 = __builtin_amdgcn_readfirstlane(tokRS[0]);
        if (t0 >= 0) {
            const float* g = emb + (size_t)t0 * Ec;
            vA = g[l];
            if (l < 36) vB = g[64 + l];
        }
    }
    float vh = 0.f;     // consumer: this lane's h (row e), lanes 0-49 valid

    // ---- main loop: iter i => producer builds c[i], consumer does step i-LEAD ----
    #pragma unroll 1
    for (int i = 0; i < Tc + LEAD; ++i) {
        if (!cons) {
            // ================= PRODUCER =================
            if (i < Tc) {
                // issue next emb prefetch first (lands during/after this step)
                float nA = 0.f, nB = 0.f;
                if (i + 1 < Tc) {
                    const int tn = __builtin_amdgcn_readfirstlane(tokRS[i + 1]);
                    if (tn >= 0) {
                        const float* g = emb + (size_t)tn * Ec;
                        nA = g[l];
                        if (l < 36) nB = g[64 + l];
                    }
                }
                float acc0 = b1e, acc1 = 0.f, acc2 = 0.f, acc3 = 0.f;
                const int tcur = __builtin_amdgcn_readfirstlane(tokRS[i]);
                if (tcur >= 0) { REP100(MACCP) }     // right leaf (always, these inputs)
                if (l < 50) cring[i & 3][erow] = ((acc0 + acc1) + (acc2 + acc3));
                vA = nA; vB = nB;
            }
        } else {
            // ================= CONSUMER =================
            const int tc = i - LEAD;
            if (tc >= 0) {
                const int2 cc = ccS[tc];
                const int  li = __builtin_amdgcn_readfirstlane(cc.x);
                const int  ri = __builtin_amdgcn_readfirstlane(cc.y);
                float cv = (l < 50) ? cring[tc & 3][erow] : 0.f;
                float acc0 = 0.f, acc1 = 0.f, acc2 = 0.f, acc3 = 0.f;
                float vo = 0.f;

                if (tc >= 1 && li == Lc + tc - 1) {
                    // fast path: left = previous node. own half in vh; read other 50.
                    const float* hrow = &hist[(size_t)(tc - 1) * Ec];
                    if (l < 50) vo = hrow[(wv == 0) ? (50 + l) : l];
                    if (wv == 0) { REP100(MACC0) } else { REP100(MACC1) }
                } else if (li >= Lc) {
                    // generic internal node n (zeros if unwritten)
                    const int n = min(li - Lc, Tc - 1);
                    const float* hrow = &hist[(size_t)n * Ec];
                    vA = hrow[l];
                    vB = (l < 36) ? hrow[64 + l] : 0.f;
                    REP100(MACCP)
                } else {
                    // left leaf (t==0 for these inputs): emb row, coalesced per-lane
                    const int tl = __builtin_amdgcn_readfirstlane(tokLS[tc]);
                    const float* g = emb + (size_t)max(tl, 0) * Ec;
                    vA = g[l];
                    vB = (l < 36) ? g[64 + l] : 0.f;
                    REP100(MACCP)
                }

                if (ri >= Lc) {
                    // generic right-internal (never these inputs): W1R from global, dyn readlane
                    const int n = min(ri - Lc, Tc - 1);
                    const float* hrow = &hist[(size_t)n * Ec];
                    vA = hrow[l];
                    vB = (l < 36) ? hrow[64 + l] : 0.f;
                    const float* wr = W1 + (size_t)erow * W1cols + Ec;
                    for (int k = 0; k < Ec; ++k) {
                        float hv = __int_as_float(__builtin_amdgcn_readlane(
                            __float_as_int(k < 64 ? vA : vB), k < 64 ? k : k - 64));
                        acc0 = fmaf(hv, wr[k], acc0);
                    }
                }

                const float x = ((acc0 + acc1) + (acc2 + acc3)) + cv;
                const float u = __expf(2.f * x);
                vh = 1.f - 2.f / (u + 1.f);          // tanh, exact identity
                if (l < 50) hist[(size_t)tc * Ec + erow] = vh;
            }
        }
        // one barrier per step: order DS writes -> next-step DS reads.
        // NO vmcnt drain (producer prefetch stays in flight across the barrier).
        asm volatile("s_waitcnt lgkmcnt(0)\n\ts_barrier" ::: "memory");
    }

    // ---- out[b] = sigmoid(W2 . h_254 + b2) ----
    if (cons) {
        float p = (l < 50) ? w2e * vh : 0.f;
        #pragma unroll
        for (int off = 32; off > 0; off >>= 1) p += __shfl_down(p, off, 64);
        if (l == 0) red[wv] = p;
    }
    __syncthreads();
    if (tid == 0) out[b] = 1.f / (1.f + __expf(-(red[0] + red[1] + b2[0])));
}

extern "C" void kernel_launch(void* const* d_in, const int* in_sizes, int n_in,
                              void* d_out, int out_size, void* d_ws, size_t ws_size,
                              hipStream_t stream) {
    const int*   token_ids  = (const int*)  d_in[0];
    const int*   comp_left  = (const int*)  d_in[1];
    const int*   comp_right = (const int*)  d_in[2];
    const float* emb        = (const float*)d_in[3];
    const float* W1         = (const float*)d_in[4];
    const float* b1         = (const float*)d_in[5];
    const float* W2         = (const float*)d_in[6];
    const float* b2         = (const float*)d_in[7];
    float*       out        = (float*)d_out;

    fused<<<Bc, 256, 0, stream>>>(token_ids, comp_left, comp_right,
                                  emb, W1, b1, W2, b2, out);
}